// Round 1
// baseline (874.056 us; speedup 1.0000x reference)
//
#include <hip/hip_runtime.h>
#include <cstdint>
#include <cstddef>

#define Bb 4
#define Nn 384
#define Ff 128
#define Tt 8

// ---------- helpers: packed bf16 pairs in a uint ----------
static __device__ __forceinline__ float bf_lo(unsigned int u) {
    union { unsigned int i; float f; } c; c.i = u << 16; return c.f;
}
static __device__ __forceinline__ float bf_hi(unsigned int u) {
    union { unsigned int i; float f; } c; c.i = u & 0xffff0000u; return c.f;
}
static __device__ __forceinline__ unsigned int pack2bf(float lo, float hi) {
    union { float f; unsigned int i; } ca, cb;
    ca.f = lo; cb.f = hi;
    unsigned int a = (ca.i + 0x7fffu + ((ca.i >> 16) & 1u)) >> 16;          // RNE
    unsigned int b = (cb.i + 0x7fffu + ((cb.i >> 16) & 1u)) & 0xffff0000u;  // RNE
    return a | b;
}

// ---------- K1: per-(b,n) precompute of all broadcast terms ----------
// preA[b,j,m] = node@W_m1 + graph@W_mg + b_m1 + b_mg + b_me   (the j-side + per-b terms of msgs)
// preB[b,i,m] = hidden@W_m2 + b_m2                            (the i-side term)
// triA[b,j,t] = node@W_tn1 + hidden@W_th1 + graph@(W_tg1+W_tg2) + b_tn1+b_th1+b_tg1+b_tg2+b_te1+b_te2
// triB[b,i,t] = node@W_tn2 + hidden@W_th2 + b_tn2+b_th2
__global__ __launch_bounds__(128) void k_pre(
    const float* __restrict__ node, const float* __restrict__ hidden,
    const float* __restrict__ graph,
    const float* __restrict__ W_m1, const float* __restrict__ b_m1,
    const float* __restrict__ W_m2, const float* __restrict__ b_m2,
    const float* __restrict__ b_me,
    const float* __restrict__ W_mg, const float* __restrict__ b_mg,
    const float* __restrict__ W_tn1, const float* __restrict__ b_tn1,
    const float* __restrict__ W_tn2, const float* __restrict__ b_tn2,
    const float* __restrict__ W_th1, const float* __restrict__ b_th1,
    const float* __restrict__ W_th2, const float* __restrict__ b_th2,
    const float* __restrict__ W_tg1, const float* __restrict__ b_tg1,
    const float* __restrict__ W_tg2, const float* __restrict__ b_tg2,
    const float* __restrict__ b_te1, const float* __restrict__ b_te2,
    float* __restrict__ preA, float* __restrict__ preB,
    float* __restrict__ triA, float* __restrict__ triB)
{
    int bn = blockIdx.x;          // b*Nn + n
    int b  = bn / Nn;
    int t  = threadIdx.x;         // 0..127 == output channel m
    __shared__ float sn[Ff], sh[Ff], sg[Ff];
    sn[t] = node[(size_t)bn * Ff + t];
    sh[t] = hidden[(size_t)bn * Ff + t];
    sg[t] = graph[b * Ff + t];
    __syncthreads();

    float a = b_m1[t] + b_mg[t] + b_me[t];
    float h = b_m2[t];
    for (int k = 0; k < Ff; ++k) {
        a = fmaf(sn[k], W_m1[k * Ff + t], a);
        a = fmaf(sg[k], W_mg[k * Ff + t], a);
        h = fmaf(sh[k], W_m2[k * Ff + t], h);
    }
    preA[(size_t)bn * Ff + t] = a;
    preB[(size_t)bn * Ff + t] = h;

    if (t < 2 * Tt) {
        int tt = t & 7;
        if (t < Tt) {
            float v = b_tn1[tt] + b_th1[tt] + b_tg1[tt] + b_tg2[tt] + b_te1[tt] + b_te2[tt];
            for (int k = 0; k < Ff; ++k)
                v += sn[k] * W_tn1[k * Tt + tt] + sh[k] * W_th1[k * Tt + tt]
                   + sg[k] * (W_tg1[k * Tt + tt] + W_tg2[k * Tt + tt]);
            triA[bn * Tt + tt] = v;
        } else {
            float v = b_tn2[tt] + b_th2[tt];
            for (int k = 0; k < Ff; ++k)
                v += sn[k] * W_tn2[k * Tt + tt] + sh[k] * W_th2[k * Tt + tt];
            triB[bn * Tt + tt] = v;
        }
    }
}

// ---------- K2: tri_msgs. One block per (b,i); streams edge[b,i,:,:] contiguously ----------
__global__ __launch_bounds__(256) void k_tri(
    const float* __restrict__ edge,
    const float* __restrict__ W_te1, const float* __restrict__ W_te2,
    const float* __restrict__ triA, const float* __restrict__ triB,
    float* __restrict__ tri_out)
{
    int bi = blockIdx.x;          // b*Nn + i
    int b  = bi / Nn;
    int t  = threadIdx.x;
    __shared__ float sWT[Tt * 132];   // combined (W_te1+W_te2), transposed [t][k], padded stride
    __shared__ float sA[64 * 132];    // 64 edge rows, padded stride 132 (breaks pow2 bank stride)
    __shared__ float sB[Tt];

    for (int idx = t; idx < Ff * Tt; idx += 256) {
        int k = idx >> 3, tt = idx & 7;
        sWT[tt * 132 + k] = W_te1[k * Tt + tt] + W_te2[k * Tt + tt];
    }
    if (t < Tt) sB[t] = triB[bi * Tt + t];

    const float* eb = edge + (size_t)bi * (Nn * Ff);
    int row = t >> 2;             // 0..63 : j within chunk
    int tq  = (t & 3) * 2;        // output pair {tq, tq+1}

    for (int c = 0; c < Nn / 64; ++c) {
        __syncthreads();
        const float4* src = (const float4*)(eb + (size_t)c * 64 * Ff);
        #pragma unroll
        for (int s = 0; s < 8; ++s) {
            int idx = t + s * 256;            // 0..2047 float4s
            int r = idx >> 5, k4 = idx & 31;
            *((float4*)&sA[r * 132 + k4 * 4]) = src[idx];
        }
        __syncthreads();

        const float4* a4  = (const float4*)&sA[row * 132];
        const float4* w4a = (const float4*)&sWT[tq * 132];
        const float4* w4b = (const float4*)&sWT[(tq + 1) * 132];
        float d0 = 0.f, d1 = 0.f;
        #pragma unroll 8
        for (int k4 = 0; k4 < 32; ++k4) {
            float4 e  = a4[k4];
            float4 wa = w4a[k4];
            float4 wb = w4b[k4];
            d0 += e.x * wa.x + e.y * wa.y + e.z * wa.z + e.w * wa.w;
            d1 += e.x * wb.x + e.y * wb.y + e.z * wb.z + e.w * wb.w;
        }
        int j  = c * 64 + row;
        int ja = (b * Nn + j) * Tt;
        float r0 = fmaxf(d0 + triA[ja + tq]     + sB[tq],     0.f);
        float r1 = fmaxf(d1 + triA[ja + tq + 1] + sB[tq + 1], 0.f);
        *((float2*)&tri_out[((size_t)bi * Nn + j) * Tt + tq]) = make_float2(r0, r1);
    }
}

// ---------- K3: msgs GEMM + masked max over senders i. One block per (b,j). ----------
// block 256 = 32 (tx: 4 m each) x 8 (ty: 4 rows each); chunk = 32 i-rows.
// W_me kept in LDS as packed bf16 pairs (32 KB) -> total LDS 48.9 KB -> 3 blocks/CU.
__global__ __launch_bounds__(256) void k_msg(
    const float* __restrict__ edge, const float* __restrict__ W_me,
    const float* __restrict__ adj,
    const float* __restrict__ preA, const float* __restrict__ preB,
    float* __restrict__ msgs_max)
{
    int bj = blockIdx.x;          // b*Nn + j
    int b = bj / Nn, j = bj % Nn;
    int t = threadIdx.x;
    int tx = t & 31, ty = t >> 5;
    __shared__ unsigned int sW[Ff * 64];   // [k][m/2] packed bf16 pairs
    __shared__ float sA[32 * 132];         // 32 edge rows, padded

    for (int u = t; u < Ff * 64; u += 256) {
        int k = u >> 6, p = (u & 63) * 2;
        sW[u] = pack2bf(W_me[k * Ff + p], W_me[k * Ff + p + 1]);
    }

    int m0 = tx * 4;
    float4 pa = *(const float4*)&preA[(size_t)bj * Ff + m0];
    float mx0 = -1e30f, mx1 = -1e30f, mx2 = -1e30f, mx3 = -1e30f;

    for (int c = 0; c < Nn / 32; ++c) {
        __syncthreads();
        #pragma unroll
        for (int s = 0; s < 4; ++s) {
            int idx = t + s * 256;            // 0..1023 float4s
            int r = idx >> 5, k4 = idx & 31;
            int i = c * 32 + r;
            *((float4*)&sA[r * 132 + k4 * 4]) =
                *(const float4*)&edge[((size_t)(b * Nn + i) * Nn + j) * Ff + k4 * 4];
        }
        __syncthreads();

        float acc[4][4];
        #pragma unroll
        for (int rr = 0; rr < 4; ++rr)
            #pragma unroll
            for (int mm = 0; mm < 4; ++mm) acc[rr][mm] = 0.f;

        for (int k4 = 0; k4 < 32; ++k4) {
            float a[4][4];
            #pragma unroll
            for (int rr = 0; rr < 4; ++rr)
                *((float4*)a[rr]) = *(const float4*)&sA[(ty * 4 + rr) * 132 + k4 * 4];
            #pragma unroll
            for (int kk = 0; kk < 4; ++kk) {
                uint2 wp = *(const uint2*)&sW[(k4 * 4 + kk) * 64 + tx * 2];
                float w0 = bf_lo(wp.x), w1 = bf_hi(wp.x);
                float w2 = bf_lo(wp.y), w3 = bf_hi(wp.y);
                #pragma unroll
                for (int rr = 0; rr < 4; ++rr) {
                    float e = a[rr][kk];
                    acc[rr][0] = fmaf(e, w0, acc[rr][0]);
                    acc[rr][1] = fmaf(e, w1, acc[rr][1]);
                    acc[rr][2] = fmaf(e, w2, acc[rr][2]);
                    acc[rr][3] = fmaf(e, w3, acc[rr][3]);
                }
            }
        }
        #pragma unroll
        for (int rr = 0; rr < 4; ++rr) {
            int i = c * 32 + ty * 4 + rr;
            float av  = adj[((size_t)b * Nn + i) * Nn + j];
            float4 pb = *(const float4*)&preB[((size_t)(b * Nn + i)) * Ff + m0];
            mx0 = fmaxf(mx0, (acc[rr][0] + pa.x + pb.x) * av);
            mx1 = fmaxf(mx1, (acc[rr][1] + pa.y + pb.y) * av);
            mx2 = fmaxf(mx2, (acc[rr][2] + pa.z + pb.z) * av);
            mx3 = fmaxf(mx3, (acc[rr][3] + pa.w + pb.w) * av);
        }
    }

    // cross-ty max reduction (reuse sA)
    __syncthreads();
    *((float4*)&sA[ty * Ff + m0]) = make_float4(mx0, mx1, mx2, mx3);
    __syncthreads();
    if (t < Ff) {
        float v = sA[t];
        #pragma unroll
        for (int g = 1; g < 8; ++g) v = fmaxf(v, sA[g * Ff + t]);
        msgs_max[(size_t)bj * Ff + t] = v;
    }
}

// ---------- K4: ret = node@W_o1 + hidden@W_o2 + msgs_max@W_o3 + biases ----------
__global__ __launch_bounds__(128) void k_out(
    const float* __restrict__ node, const float* __restrict__ hidden,
    const float* __restrict__ msgs_max,
    const float* __restrict__ W_o1, const float* __restrict__ b_o1,
    const float* __restrict__ W_o2, const float* __restrict__ b_o2,
    const float* __restrict__ W_o3, const float* __restrict__ b_o3,
    float* __restrict__ out)
{
    int bn = blockIdx.x;
    int t  = threadIdx.x;
    __shared__ float sn[Ff], sh[Ff], sm[Ff];
    sn[t] = node[(size_t)bn * Ff + t];
    sh[t] = hidden[(size_t)bn * Ff + t];
    sm[t] = msgs_max[(size_t)bn * Ff + t];
    __syncthreads();
    float v = b_o1[t] + b_o2[t] + b_o3[t];
    for (int k = 0; k < Ff; ++k) {
        v = fmaf(sn[k], W_o1[k * Ff + t], v);
        v = fmaf(sh[k], W_o2[k * Ff + t], v);
        v = fmaf(sm[k], W_o3[k * Ff + t], v);
    }
    out[(size_t)bn * Ff + t] = v;
}

extern "C" void kernel_launch(void* const* d_in, const int* in_sizes, int n_in,
                              void* d_out, int out_size, void* d_ws, size_t ws_size,
                              hipStream_t stream)
{
    const float* node   = (const float*)d_in[0];
    const float* edge   = (const float*)d_in[1];
    const float* graph  = (const float*)d_in[2];
    const float* adj    = (const float*)d_in[3];
    const float* hidden = (const float*)d_in[4];
    const float* W_m1 = (const float*)d_in[5];  const float* b_m1 = (const float*)d_in[6];
    const float* W_m2 = (const float*)d_in[7];  const float* b_m2 = (const float*)d_in[8];
    const float* W_me = (const float*)d_in[9];  const float* b_me = (const float*)d_in[10];
    const float* W_mg = (const float*)d_in[11]; const float* b_mg = (const float*)d_in[12];
    const float* W_o1 = (const float*)d_in[13]; const float* b_o1 = (const float*)d_in[14];
    const float* W_o2 = (const float*)d_in[15]; const float* b_o2 = (const float*)d_in[16];
    const float* W_o3 = (const float*)d_in[17]; const float* b_o3 = (const float*)d_in[18];
    const float* W_tn1 = (const float*)d_in[19]; const float* b_tn1 = (const float*)d_in[20];
    const float* W_tn2 = (const float*)d_in[21]; const float* b_tn2 = (const float*)d_in[22];
    const float* W_th1 = (const float*)d_in[23]; const float* b_th1 = (const float*)d_in[24];
    const float* W_th2 = (const float*)d_in[25]; const float* b_th2 = (const float*)d_in[26];
    const float* W_te1 = (const float*)d_in[27]; const float* b_te1 = (const float*)d_in[28];
    const float* W_te2 = (const float*)d_in[29]; const float* b_te2 = (const float*)d_in[30];
    const float* W_tg1 = (const float*)d_in[31]; const float* b_tg1 = (const float*)d_in[32];
    const float* W_tg2 = (const float*)d_in[33]; const float* b_tg2 = (const float*)d_in[34];

    float* ws   = (float*)d_ws;
    float* preA = ws;                     // 196608 floats
    float* preB = preA + 196608;          // 196608
    float* triA = preB + 196608;          // 12288
    float* triB = triA + 12288;           // 12288
    float* msgs = triB + 12288;           // 196608  (total 2.46 MB)

    float* ret = (float*)d_out;           // (4,384,128)
    float* tri = ret + (size_t)Bb * Nn * Ff;  // (4,384,384,8)

    hipLaunchKernelGGL(k_pre, dim3(Bb * Nn), dim3(128), 0, stream,
        node, hidden, graph, W_m1, b_m1, W_m2, b_m2, b_me, W_mg, b_mg,
        W_tn1, b_tn1, W_tn2, b_tn2, W_th1, b_th1, W_th2, b_th2,
        W_tg1, b_tg1, W_tg2, b_tg2, b_te1, b_te2,
        preA, preB, triA, triB);
    hipLaunchKernelGGL(k_tri, dim3(Bb * Nn), dim3(256), 0, stream,
        edge, W_te1, W_te2, triA, triB, tri);
    hipLaunchKernelGGL(k_msg, dim3(Bb * Nn), dim3(256), 0, stream,
        edge, W_me, adj, preA, preB, msgs);
    hipLaunchKernelGGL(k_out, dim3(Bb * Nn), dim3(128), 0, stream,
        node, hidden, msgs, W_o1, b_o1, W_o2, b_o2, W_o3, b_o3, ret);
}

// Round 2
// 614.594 us; speedup vs baseline: 1.4222x; 1.4222x over previous
//
#include <hip/hip_runtime.h>
#include <cstdint>
#include <cstddef>

#define Bb 4
#define Nn 384
#define Ff 128
#define Tt 8

typedef __attribute__((ext_vector_type(8))) __bf16 bf16x8;
typedef __attribute__((ext_vector_type(4))) float fv4;

// ---------- bf16 helpers ----------
static __device__ __forceinline__ unsigned int pack2bf(float lo, float hi) {
    union { float f; unsigned int i; } ca, cb;
    ca.f = lo; cb.f = hi;
    unsigned int a = (ca.i + 0x7fffu + ((ca.i >> 16) & 1u)) >> 16;          // RNE
    unsigned int b = (cb.i + 0x7fffu + ((cb.i >> 16) & 1u)) & 0xffff0000u;  // RNE
    return a | b;
}
static __device__ __forceinline__ unsigned short f2bf(float f) {
    union { float f; unsigned int i; } c; c.f = f;
    return (unsigned short)((c.i + 0x7fffu + ((c.i >> 16) & 1u)) >> 16);
}
static __device__ __forceinline__ float bf2f(unsigned short u) {
    union { unsigned int i; float f; } c; c.i = ((unsigned int)u) << 16;
    return c.f;
}

// ---------- K1: per-(b,n) precompute of all broadcast terms ----------
__global__ __launch_bounds__(128) void k_pre(
    const float* __restrict__ node, const float* __restrict__ hidden,
    const float* __restrict__ graph,
    const float* __restrict__ W_m1, const float* __restrict__ b_m1,
    const float* __restrict__ W_m2, const float* __restrict__ b_m2,
    const float* __restrict__ b_me,
    const float* __restrict__ W_mg, const float* __restrict__ b_mg,
    const float* __restrict__ W_tn1, const float* __restrict__ b_tn1,
    const float* __restrict__ W_tn2, const float* __restrict__ b_tn2,
    const float* __restrict__ W_th1, const float* __restrict__ b_th1,
    const float* __restrict__ W_th2, const float* __restrict__ b_th2,
    const float* __restrict__ W_tg1, const float* __restrict__ b_tg1,
    const float* __restrict__ W_tg2, const float* __restrict__ b_tg2,
    const float* __restrict__ b_te1, const float* __restrict__ b_te2,
    float* __restrict__ preA, float* __restrict__ preB,
    float* __restrict__ triA, float* __restrict__ triB)
{
    int bn = blockIdx.x;          // b*Nn + n
    int b  = bn / Nn;
    int t  = threadIdx.x;         // 0..127 == output channel m
    __shared__ float sn[Ff], sh[Ff], sg[Ff];
    sn[t] = node[(size_t)bn * Ff + t];
    sh[t] = hidden[(size_t)bn * Ff + t];
    sg[t] = graph[b * Ff + t];
    __syncthreads();

    float a = b_m1[t] + b_mg[t] + b_me[t];
    float h = b_m2[t];
    for (int k = 0; k < Ff; ++k) {
        a = fmaf(sn[k], W_m1[k * Ff + t], a);
        a = fmaf(sg[k], W_mg[k * Ff + t], a);
        h = fmaf(sh[k], W_m2[k * Ff + t], h);
    }
    preA[(size_t)bn * Ff + t] = a;
    preB[(size_t)bn * Ff + t] = h;

    if (t < 2 * Tt) {
        int tt = t & 7;
        if (t < Tt) {
            float v = b_tn1[tt] + b_th1[tt] + b_tg1[tt] + b_tg2[tt] + b_te1[tt] + b_te2[tt];
            for (int k = 0; k < Ff; ++k)
                v += sn[k] * W_tn1[k * Tt + tt] + sh[k] * W_th1[k * Tt + tt]
                   + sg[k] * (W_tg1[k * Tt + tt] + W_tg2[k * Tt + tt]);
            triA[bn * Tt + tt] = v;
        } else {
            float v = b_tn2[tt] + b_th2[tt];
            for (int k = 0; k < Ff; ++k)
                v += sn[k] * W_tn2[k * Tt + tt] + sh[k] * W_th2[k * Tt + tt];
            triB[bn * Tt + tt] = v;
        }
    }
}

// ---------- K2: build W_T bf16 [144 rows][136 stride] in ws ----------
// rows 0..127: W_me^T (row m holds W_me[k][m], k=0..127)
// rows 128..135: (W_te1+W_te2)^T ; rows 136..143: zeros (OOB-read pad for tri B-frag)
__global__ __launch_bounds__(256) void k_prew(
    const float* __restrict__ W_me, const float* __restrict__ W_te1,
    const float* __restrict__ W_te2, unsigned short* __restrict__ wt)
{
    int idx = blockIdx.x * 256 + threadIdx.x;
    if (idx >= 144 * 136) return;
    int row = idx / 136, kc = idx % 136;
    float v = 0.f;
    if (kc < 128) {
        if (row < 128)      v = W_me[kc * Ff + row];
        else if (row < 136) v = W_te1[kc * Tt + (row - 128)] + W_te2[kc * Tt + (row - 128)];
    }
    wt[idx] = f2bf(v);
}

// ---------- K3: fused edge pass: GEMM (msgs 128 + tri 8) + online masked max ----------
// grid 1152 = b(4) x jblk(12) x iblk(24); block tile = 16 i x 32 j; chunks of 2 i.
#define EST 136                                  // ushort stride per LDS row (272 B: 16B-aligned frags)
#define LDS_E_BYTES (64 * EST * 2)               // 17408
#define LDS_WT_OFF  LDS_E_BYTES
#define LDS_WT_BYTES (144 * EST * 2)             // 39168
#define LDS_ADJ_OFF (LDS_WT_OFF + LDS_WT_BYTES)  // 56576
#define LDS_TOTAL   (LDS_ADJ_OFF + 512 * 2)      // 57600

__global__ __launch_bounds__(256, 2) void k_main(
    const float* __restrict__ edge, const float* __restrict__ adj,
    const unsigned short* __restrict__ wt,
    const float* __restrict__ preB,
    const float* __restrict__ triA, const float* __restrict__ triB,
    unsigned short* __restrict__ partial,   // [24][4][384][128] bf16
    float* __restrict__ azp,                // [24][1536]
    float* __restrict__ tri_out)
{
    __shared__ char smem[LDS_TOTAL];
    unsigned short* E   = (unsigned short*)smem;
    unsigned short* WT  = (unsigned short*)(smem + LDS_WT_OFF);
    unsigned short* ADJ = (unsigned short*)(smem + LDS_ADJ_OFF);

    int bx   = blockIdx.x;
    int iblk = bx % 24, jblk = (bx / 24) % 12, b = bx / 288;
    int i0 = iblk * 16, j0 = jblk * 32;
    int t    = threadIdx.x;
    int lane = t & 63, w = t >> 6;
    int l15  = lane & 15, quad = lane >> 4;
    int ih = w >> 1, jh = w & 1;              // wave -> (i within chunk, j half)
    int rowbase = ih * 32 + jh * 16;          // wave's 16 LDS rows

    // stage W_T (once): 39168 B as uint4
    for (int idx = t; idx < LDS_WT_BYTES / 16; idx += 256)
        ((uint4*)WT)[idx] = ((const uint4*)wt)[idx];
    // stage adj tile 16 i x 32 j as bf16 (exact for 0/1)
    for (int idx = t; idx < 512; idx += 256) {
        int il = idx >> 5, jl = idx & 31;
        ADJ[idx] = f2bf(adj[(size_t)(b * Nn + i0 + il) * Nn + j0 + jl]);
    }

    float mx[8][4];
    #pragma unroll
    for (int nt = 0; nt < 8; ++nt)
        #pragma unroll
        for (int r = 0; r < 4; ++r) mx[nt][r] = -1e30f;

    for (int c = 0; c < 8; ++c) {
        __syncthreads();
        // stage E chunk: 2 i x 32 j x 128 k fp32 -> bf16 (2048 float4 / 256 thr)
        const size_t base = ((size_t)(b * Nn + i0 + c * 2) * Nn + j0) * Ff;
        #pragma unroll
        for (int s = 0; s < 8; ++s) {
            int u = t + s * 256;
            int k4 = u & 31, row = u >> 5;
            int il2 = row >> 5, jl2 = row & 31;
            float4 v = *(const float4*)&edge[base + (size_t)il2 * Nn * Ff + (size_t)jl2 * Ff + k4 * 4];
            *(uint2*)&E[row * EST + k4 * 4] = make_uint2(pack2bf(v.x, v.y), pack2bf(v.z, v.w));
        }
        __syncthreads();

        fv4 acc[8]; fv4 at;
        #pragma unroll
        for (int nt = 0; nt < 8; ++nt) acc[nt] = (fv4){0.f, 0.f, 0.f, 0.f};
        at = (fv4){0.f, 0.f, 0.f, 0.f};

        #pragma unroll
        for (int kk = 0; kk < 4; ++kk) {
            int ko = kk * 32 + quad * 8;
            bf16x8 a  = *(const bf16x8*)&E[(rowbase + l15) * EST + ko];
            bf16x8 bt = *(const bf16x8*)&WT[(128 + l15) * EST + ko];
            at = __builtin_amdgcn_mfma_f32_16x16x32_bf16(a, bt, at, 0, 0, 0);
            #pragma unroll
            for (int nt = 0; nt < 8; ++nt) {
                bf16x8 bq = *(const bf16x8*)&WT[(nt * 16 + l15) * EST + ko];
                acc[nt] = __builtin_amdgcn_mfma_f32_16x16x32_bf16(a, bq, acc[nt], 0, 0, 0);
            }
        }

        // epilogue: online masked max (additive mask) + tri write
        int il  = c * 2 + ih;
        int i_g = i0 + il;
        const float* pbp = &preB[(size_t)(b * Nn + i_g) * Ff];
        float pbv[8];
        #pragma unroll
        for (int nt = 0; nt < 8; ++nt) pbv[nt] = pbp[nt * 16 + l15];
        float tbv = triB[(b * Nn + i_g) * Tt + (l15 & 7)];
        #pragma unroll
        for (int r = 0; r < 4; ++r) {
            int jl = jh * 16 + quad * 4 + r;
            float adjv = bf2f(ADJ[il * 32 + jl]);
            float mr = fmaf(adjv, 1e30f, -1e30f);     // adj=1 -> 0, adj=0 -> -1e30
            #pragma unroll
            for (int nt = 0; nt < 8; ++nt)
                mx[nt][r] = fmaxf(mx[nt][r], acc[nt][r] + pbv[nt] + mr);
            float tv = at[r] + triA[(b * Nn + j0 + jl) * Tt + (l15 & 7)] + tbv;
            if (l15 < 8)
                tri_out[((size_t)(b * Nn + i_g) * Nn + j0 + jl) * Tt + l15] = fmaxf(tv, 0.f);
        }
    }

    // cross-wave max: waves {w, w+2} share the same j-half, different i
    __syncthreads();
    float* S = (float*)smem;                  // 4 slices x 16 j x 128 m = 32 KB (over E+WT area)
    #pragma unroll
    for (int r = 0; r < 4; ++r) {
        int jq = quad * 4 + r;
        #pragma unroll
        for (int nt = 0; nt < 8; ++nt)
            S[w * 2048 + jq * 128 + nt * 16 + l15] = mx[nt][r];
    }
    if (t < 32) {                             // anyzero per j (ADJ area untouched by S)
        int any0 = 0;
        for (int il2 = 0; il2 < 16; ++il2) any0 |= (ADJ[il2 * 32 + t] == 0);
        azp[iblk * 1536 + b * Nn + j0 + t] = any0 ? 1.f : 0.f;
    }
    __syncthreads();
    #pragma unroll
    for (int e = 0; e < 16; ++e) {
        int idx = e * 256 + t;                // jl*128 + m
        int jl = idx >> 7, m = idx & 127;
        int jh2 = jl >> 4, jq = jl & 15;
        float v = fmaxf(S[jh2 * 2048 + jq * 128 + m], S[(jh2 + 2) * 2048 + jq * 128 + m]);
        partial[(size_t)iblk * 196608 + (size_t)(b * Nn + j0 + jl) * Ff + m] = f2bf(v);
    }
}

// ---------- K4: reduce partials over 24 iblks, add preA, anyzero clamp ----------
__global__ __launch_bounds__(256) void k_red(
    const unsigned short* __restrict__ partial, const float* __restrict__ azp,
    const float* __restrict__ preA, float* __restrict__ msgs)
{
    int flat = blockIdx.x * 256 + threadIdx.x;   // < 196608
    float v = -1e30f;
    #pragma unroll
    for (int ib = 0; ib < 24; ++ib)
        v = fmaxf(v, bf2f(partial[(size_t)ib * 196608 + flat]));
    float az = 0.f;
    int bj = flat >> 7;
    #pragma unroll
    for (int ib = 0; ib < 24; ++ib) az += azp[ib * 1536 + bj];
    v += preA[flat];
    if (az > 0.5f) v = fmaxf(v, 0.f);
    msgs[flat] = v;
}

// ---------- K5: ret = node@W_o1 + hidden@W_o2 + msgs@W_o3 + biases ----------
__global__ __launch_bounds__(128) void k_out(
    const float* __restrict__ node, const float* __restrict__ hidden,
    const float* __restrict__ msgs_max,
    const float* __restrict__ W_o1, const float* __restrict__ b_o1,
    const float* __restrict__ W_o2, const float* __restrict__ b_o2,
    const float* __restrict__ W_o3, const float* __restrict__ b_o3,
    float* __restrict__ out)
{
    int bn = blockIdx.x;
    int t  = threadIdx.x;
    __shared__ float sn[Ff], sh[Ff], sm[Ff];
    sn[t] = node[(size_t)bn * Ff + t];
    sh[t] = hidden[(size_t)bn * Ff + t];
    sm[t] = msgs_max[(size_t)bn * Ff + t];
    __syncthreads();
    float v = b_o1[t] + b_o2[t] + b_o3[t];
    for (int k = 0; k < Ff; ++k) {
        v = fmaf(sn[k], W_o1[k * Ff + t], v);
        v = fmaf(sh[k], W_o2[k * Ff + t], v);
        v = fmaf(sm[k], W_o3[k * Ff + t], v);
    }
    out[(size_t)bn * Ff + t] = v;
}

extern "C" void kernel_launch(void* const* d_in, const int* in_sizes, int n_in,
                              void* d_out, int out_size, void* d_ws, size_t ws_size,
                              hipStream_t stream)
{
    const float* node   = (const float*)d_in[0];
    const float* edge   = (const float*)d_in[1];
    const float* graph  = (const float*)d_in[2];
    const float* adj    = (const float*)d_in[3];
    const float* hidden = (const float*)d_in[4];
    const float* W_m1 = (const float*)d_in[5];  const float* b_m1 = (const float*)d_in[6];
    const float* W_m2 = (const float*)d_in[7];  const float* b_m2 = (const float*)d_in[8];
    const float* W_me = (const float*)d_in[9];  const float* b_me = (const float*)d_in[10];
    const float* W_mg = (const float*)d_in[11]; const float* b_mg = (const float*)d_in[12];
    const float* W_o1 = (const float*)d_in[13]; const float* b_o1 = (const float*)d_in[14];
    const float* W_o2 = (const float*)d_in[15]; const float* b_o2 = (const float*)d_in[16];
    const float* W_o3 = (const float*)d_in[17]; const float* b_o3 = (const float*)d_in[18];
    const float* W_tn1 = (const float*)d_in[19]; const float* b_tn1 = (const float*)d_in[20];
    const float* W_tn2 = (const float*)d_in[21]; const float* b_tn2 = (const float*)d_in[22];
    const float* W_th1 = (const float*)d_in[23]; const float* b_th1 = (const float*)d_in[24];
    const float* W_th2 = (const float*)d_in[25]; const float* b_th2 = (const float*)d_in[26];
    const float* W_te1 = (const float*)d_in[27]; const float* b_te1 = (const float*)d_in[28];
    const float* W_te2 = (const float*)d_in[29]; const float* b_te2 = (const float*)d_in[30];
    const float* W_tg1 = (const float*)d_in[31]; const float* b_tg1 = (const float*)d_in[32];
    const float* W_tg2 = (const float*)d_in[33]; const float* b_tg2 = (const float*)d_in[34];

    float* ws   = (float*)d_ws;
    float* preA = ws;                              // 196608 f
    float* preB = preA + 196608;                   // 196608 f
    float* triA = preB + 196608;                   // 12288 f
    float* triB = triA + 12288;                    // 12288 f
    float* msgs = triB + 12288;                    // 196608 f
    unsigned short* wt      = (unsigned short*)(msgs + 196608);       // 19584 us (byte 2457600)
    unsigned short* partial = wt + 19584;                             // 4718592 us
    float* azp              = (float*)(partial + 4718592);            // 36864 f  (total ~12.1 MB)

    float* ret = (float*)d_out;                    // (4,384,128)
    float* tri = ret + (size_t)Bb * Nn * Ff;       // (4,384,384,8)

    hipLaunchKernelGGL(k_pre, dim3(Bb * Nn), dim3(128), 0, stream,
        node, hidden, graph, W_m1, b_m1, W_m2, b_m2, b_me, W_mg, b_mg,
        W_tn1, b_tn1, W_tn2, b_tn2, W_th1, b_th1, W_th2, b_th2,
        W_tg1, b_tg1, W_tg2, b_tg2, b_te1, b_te2,
        preA, preB, triA, triB);
    hipLaunchKernelGGL(k_prew, dim3(77), dim3(256), 0, stream,
        W_me, W_te1, W_te2, wt);
    hipLaunchKernelGGL(k_main, dim3(Bb * 12 * 24), dim3(256), 0, stream,
        edge, adj, wt, preB, triA, triB, partial, azp, tri);
    hipLaunchKernelGGL(k_red, dim3(768), dim3(256), 0, stream,
        partial, azp, preA, msgs);
    hipLaunchKernelGGL(k_out, dim3(Bb * Nn), dim3(128), 0, stream,
        node, hidden, msgs, W_o1, b_o1, W_o2, b_o2, W_o3, b_o3, ret);
}